// Round 6
// baseline (3114.974 us; speedup 1.0000x reference)
//
#include <hip/hip_runtime.h>
#include <stdint.h>

#define M_NODES 100000
#define NUM_EDGES 3200000
#define IN_DIM 512
#define HIDDEN 256
#define NCLS 64

typedef __bf16 bf16x8 __attribute__((ext_vector_type(8)));
typedef float floatx4 __attribute__((ext_vector_type(4)));

// ---- workspace layout (bytes) ----
#define WS_ROWPTR 0
#define WS_W1T    400016
#define WS_W2T    662160
#define WS_H1     694928
#define WS_BB     694928      // alias of h1 (dead after gemm2)
#define WS_FA     51894928
#define WS_FB     77494928
#define WS_BA     103094928

// ---------------- weight transpose + bf16 convert ----------------
__global__ __launch_bounds__(256) void prep_weights(
    const float* __restrict__ W1, const float* __restrict__ W2,
    unsigned short* __restrict__ w1t, unsigned short* __restrict__ w2t) {
  int tid = blockIdx.x * 256 + threadIdx.x;
  if (tid < IN_DIM * HIDDEN) {
    int n = tid >> 9;
    int k = tid & 511;
    __bf16 v = (__bf16)W1[k * HIDDEN + n];
    w1t[tid] = __builtin_bit_cast(unsigned short, v);
  } else {
    int idx = tid - IN_DIM * HIDDEN;
    if (idx < HIDDEN * NCLS) {
      int n = idx >> 8;
      int k = idx & 255;
      __bf16 v = (__bf16)W2[k * NCLS + n];
      w2t[idx] = __builtin_bit_cast(unsigned short, v);
    }
  }
}

// ---------------- row_ptr via binary search over sorted edge_row ----------------
__global__ __launch_bounds__(256) void build_rowptr(
    const int* __restrict__ erow, int* __restrict__ rp) {
  int r = blockIdx.x * 256 + threadIdx.x;
  if (r > M_NODES) return;
  if (r == M_NODES) { rp[r] = NUM_EDGES; return; }
  int lo = 0, hi = NUM_EDGES;
  while (lo < hi) {
    int mid = (lo + hi) >> 1;
    if (erow[mid] < r) lo = mid + 1; else hi = mid;
  }
  rp[r] = lo;
}

// ---------------- GEMM1: h1 = relu(x @ W1 + b1), bf16 out ----------------
// Block = 32 rows; 4 waves split N into 64-col slices (acc[2][4] = 32 AGPRs).
// x tile staged in LDS; NEXT tile prefetched into registers before the MFMA
// phase so global latency hides under compute instead of stalling at barrier.
__global__ __launch_bounds__(256) void gemm1(
    const float* __restrict__ x, const unsigned short* __restrict__ w1t,
    const float* __restrict__ b1, unsigned short* __restrict__ h1) {
  __shared__ float xs[32 * 68];
  const int wave = threadIdx.x >> 6, lane = threadIdx.x & 63;
  const int m0 = blockIdx.x * 32;
  const int n0 = wave * 64;
  const int l15 = lane & 15, quad = lane >> 4;
  const int t = threadIdx.x;

  // prefetch tile 0
  floatx4 pre[2];
#pragma unroll
  for (int j = 0; j < 2; j++) {
    const int i = t * 2 + j;
    pre[j] = *(const floatx4*)(x + (size_t)(m0 + (i >> 4)) * IN_DIM + (i & 15) * 4);
  }

  floatx4 acc[2][4] = {};
  for (int kb = 0; kb < IN_DIM; kb += 64) {
    __syncthreads();  // previous tile's readers done
#pragma unroll
    for (int j = 0; j < 2; j++) {
      const int i = t * 2 + j;
      *(floatx4*)(xs + (i >> 4) * 68 + (i & 15) * 4) = pre[j];
    }
    __syncthreads();
    if (kb + 64 < IN_DIM) {
#pragma unroll
      for (int j = 0; j < 2; j++) {
        const int i = t * 2 + j;
        pre[j] = *(const floatx4*)(x + (size_t)(m0 + (i >> 4)) * IN_DIM + kb + 64 + (i & 15) * 4);
      }
    }

    bf16x8 afrag[2][2];
    bf16x8 bfrag[2][4];
#pragma unroll
    for (int ks = 0; ks < 2; ks++) {
#pragma unroll
      for (int tm = 0; tm < 2; tm++) {
        const float* p = xs + (tm * 16 + l15) * 68 + ks * 32 + quad * 8;
        floatx4 a0 = *(const floatx4*)p;
        floatx4 a1 = *(const floatx4*)(p + 4);
        bf16x8 f;
        f[0] = (__bf16)a0[0]; f[1] = (__bf16)a0[1]; f[2] = (__bf16)a0[2]; f[3] = (__bf16)a0[3];
        f[4] = (__bf16)a1[0]; f[5] = (__bf16)a1[1]; f[6] = (__bf16)a1[2]; f[7] = (__bf16)a1[3];
        afrag[ks][tm] = f;
      }
      const int k = kb + ks * 32 + quad * 8;
#pragma unroll
      for (int tn = 0; tn < 4; tn++)
        bfrag[ks][tn] = *(const bf16x8*)(w1t + (size_t)(n0 + tn * 16 + l15) * IN_DIM + k);
    }
#pragma unroll
    for (int ks = 0; ks < 2; ks++)
#pragma unroll
      for (int tm = 0; tm < 2; tm++)
#pragma unroll
        for (int tn = 0; tn < 4; tn++)
          acc[tm][tn] = __builtin_amdgcn_mfma_f32_16x16x32_bf16(afrag[ks][tm], bfrag[ks][tn], acc[tm][tn], 0, 0, 0);
  }

#pragma unroll
  for (int tm = 0; tm < 2; tm++)
#pragma unroll
    for (int tn = 0; tn < 4; tn++) {
      const int col = n0 + tn * 16 + l15;
      const float bias = b1[col];
#pragma unroll
      for (int r = 0; r < 4; r++) {
        const int row = m0 + tm * 16 + quad * 4 + r;
        float v = acc[tm][tn][r] + bias;
        v = v > 0.0f ? v : 0.0f;
        __bf16 bv = (__bf16)v;
        h1[(size_t)row * HIDDEN + col] = __builtin_bit_cast(unsigned short, bv);
      }
    }
}

// ---------------- GEMM2: T0 = h1 @ W2 + b2 -> fp32 (fA) AND bf16 (bA) ----------------
__global__ __launch_bounds__(256) void gemm2(
    const unsigned short* __restrict__ h1, const unsigned short* __restrict__ w2t,
    const float* __restrict__ b2, float* __restrict__ t0f,
    unsigned short* __restrict__ t0b) {
  const int wave = threadIdx.x >> 6, lane = threadIdx.x & 63;
  const int m0 = blockIdx.x * 128 + wave * 32;
  if (m0 >= M_NODES) return;
  const int l15 = lane & 15, quad = lane >> 4;

  floatx4 acc[2][4] = {};
  for (int kb = 0; kb < HIDDEN; kb += 32) {
    const int k = kb + quad * 8;
    bf16x8 afrag[2], bfrag[4];
#pragma unroll
    for (int tm = 0; tm < 2; tm++)
      afrag[tm] = *(const bf16x8*)(h1 + (size_t)(m0 + tm * 16 + l15) * HIDDEN + k);
#pragma unroll
    for (int tn = 0; tn < 4; tn++)
      bfrag[tn] = *(const bf16x8*)(w2t + (size_t)(tn * 16 + l15) * HIDDEN + k);
#pragma unroll
    for (int tm = 0; tm < 2; tm++)
#pragma unroll
      for (int tn = 0; tn < 4; tn++)
        acc[tm][tn] = __builtin_amdgcn_mfma_f32_16x16x32_bf16(afrag[tm], bfrag[tn], acc[tm][tn], 0, 0, 0);
  }

#pragma unroll
  for (int tm = 0; tm < 2; tm++)
#pragma unroll
    for (int tn = 0; tn < 4; tn++) {
      const int col = tn * 16 + l15;
      const float bias = b2[col];
#pragma unroll
      for (int r = 0; r < 4; r++) {
        const int row = m0 + tm * 16 + quad * 4 + r;
        const float v = acc[tm][tn][r] + bias;
        t0f[(size_t)row * NCLS + col] = v;
        __bf16 bv = (__bf16)v;
        t0b[(size_t)row * NCLS + col] = __builtin_bit_cast(unsigned short, bv);
      }
    }
}

// ---------------- per-lane row gather (16 cols per quarter-wave) ----------------
// Lane handles (row r, col c); same accumulation order per (r,c) as before
// -> bit-identical results regardless of the block/lane re-mapping.
__device__ __forceinline__ float row_gather1(
    const int* __restrict__ rp, const int* __restrict__ cols,
    const float* __restrict__ vals, const __bf16* __restrict__ tb,
    int r, int c) {
  int e = rp[r];
  const int re = rp[r + 1];
  float a[8] = {0, 0, 0, 0, 0, 0, 0, 0};
  for (; e + 8 <= re; e += 8) {
    int ce[8];
#pragma unroll
    for (int j = 0; j < 8; j++) ce[j] = cols[e + j];
    float ge[8];
#pragma unroll
    for (int j = 0; j < 8; j++) ge[j] = (float)tb[(size_t)ce[j] * NCLS + c];
#pragma unroll
    for (int j = 0; j < 8; j++) a[j] += vals[e + j] * ge[j];
  }
  for (; e < re; ++e) a[0] += vals[e] * (float)tb[(size_t)cols[e] * NCLS + c];
  return ((a[0] + a[1]) + (a[2] + a[3])) + ((a[4] + a[5]) + (a[6] + a[7]));
}

// XCD-aware decomposition: blocks round-robin across 8 XCDs (blockIdx%8).
// Col group g = (blockIdx%8)>>1: XCD pair {2g,2g+1} only touches T[:, 16g:16g+16]
// = 100000*16*2B = 3.2 MB < 4 MB per-XCD L2 -> gathers become L2 hits.
// Wave = 4 rows x 16 cols. Block = 4 waves = 16 rows of one col group.
// grid = (100000/16) * 4 = 25000.
__device__ __forceinline__ void spmm_map(int b, int tid, int& r, int& c) {
  const int slot = b & 7;
  const int g = slot >> 1;
  const int row_blk = (b >> 3) * 2 + (slot & 1);  // 0..6249
  const int wave = tid >> 6, l = tid & 63;
  r = row_blk * 16 + wave * 4 + (l >> 4);
  c = g * 16 + (l & 15);
}

// ---------------- SpMM first: T1 = L T0 ; z = g0*T0 + g1*T1 ----------------
__global__ __launch_bounds__(256) void spmm_first(
    const int* __restrict__ rp, const int* __restrict__ cols,
    const float* __restrict__ vals, const __bf16* __restrict__ t0b,
    const float* __restrict__ t0f, float* __restrict__ t1f,
    unsigned short* __restrict__ t1b, const float* __restrict__ gamma,
    float* __restrict__ z) {
  int r, c;
  spmm_map(blockIdx.x, threadIdx.x, r, c);
  const float s = row_gather1(rp, cols, vals, t0b, r, c);
  const size_t o = (size_t)r * NCLS + c;
  t1f[o] = s;
  __bf16 bv = (__bf16)s;
  t1b[o] = __builtin_bit_cast(unsigned short, bv);
  z[o] = gamma[0] * t0f[o] + gamma[1] * s;
}

// ---------------- SpMM step: Tn = 2 L Tc - Tp (in place over Tp); z += g[k]*Tn ----
__global__ __launch_bounds__(256) void spmm_step(
    const int* __restrict__ rp, const int* __restrict__ cols,
    const float* __restrict__ vals, const __bf16* __restrict__ tcb,
    float* __restrict__ tpf, unsigned short* __restrict__ tnb,
    const float* __restrict__ gamma, int kidx, float* __restrict__ z) {
  int r, c;
  spmm_map(blockIdx.x, threadIdx.x, r, c);
  const float s = row_gather1(rp, cols, vals, tcb, r, c);
  const size_t o = (size_t)r * NCLS + c;
  const float tn = 2.0f * s - tpf[o];
  tpf[o] = tn;
  __bf16 bv = (__bf16)tn;
  tnb[o] = __builtin_bit_cast(unsigned short, bv);
  z[o] += gamma[kidx] * tn;
}

extern "C" void kernel_launch(void* const* d_in, const int* in_sizes, int n_in,
                              void* d_out, int out_size, void* d_ws, size_t ws_size,
                              hipStream_t stream) {
  const float* x     = (const float*)d_in[0];
  const int*   erow  = (const int*)d_in[1];
  const int*   ecol  = (const int*)d_in[2];
  const float* evals = (const float*)d_in[3];
  const float* W1    = (const float*)d_in[4];
  const float* b1    = (const float*)d_in[5];
  const float* W2    = (const float*)d_in[6];
  const float* b2    = (const float*)d_in[7];
  const float* gamma = (const float*)d_in[8];

  char* ws = (char*)d_ws;
  int*            rp  = (int*)(ws + WS_ROWPTR);
  unsigned short* w1t = (unsigned short*)(ws + WS_W1T);
  unsigned short* w2t = (unsigned short*)(ws + WS_W2T);
  unsigned short* h1  = (unsigned short*)(ws + WS_H1);
  float*          fA  = (float*)(ws + WS_FA);
  float*          fB  = (float*)(ws + WS_FB);
  unsigned short* bA  = (unsigned short*)(ws + WS_BA);
  unsigned short* bB  = (unsigned short*)(ws + WS_BB);
  float*          z   = (float*)d_out;

  prep_weights<<<576, 256, 0, stream>>>(W1, W2, w1t, w2t);
  build_rowptr<<<(M_NODES + 256) / 256, 256, 0, stream>>>(erow, rp);
  gemm1<<<M_NODES / 32, 256, 0, stream>>>(x, w1t, b1, h1);
  gemm2<<<(M_NODES + 127) / 128, 256, 0, stream>>>(h1, w2t, b2, fA, bA);

  const int spmm_grid = (M_NODES / 16) * 4;  // 25000
  spmm_first<<<spmm_grid, 256, 0, stream>>>(rp, ecol, evals, (const __bf16*)bA,
                                            fA, fB, bB, gamma, z);

  float*          fprev = fA;
  float*          fothr = fB;
  unsigned short* bcur  = bB;
  unsigned short* bnext = bA;
  for (int k = 2; k <= 8; ++k) {
    spmm_step<<<spmm_grid, 256, 0, stream>>>(rp, ecol, evals, (const __bf16*)bcur,
                                             fprev, bnext, gamma, k, z);
    float* tf = fprev; fprev = fothr; fothr = tf;
    unsigned short* tb = bcur; bcur = bnext; bnext = tb;
  }
}

// Round 7
// 1646.924 us; speedup vs baseline: 1.8914x; 1.8914x over previous
//
#include <hip/hip_runtime.h>
#include <stdint.h>

#define M_NODES 100000
#define NUM_EDGES 3200000
#define IN_DIM 512
#define HIDDEN 256
#define NCLS 64
#define PANEL (M_NODES * 16)   // elements per 16-col bf16 panel

typedef __bf16 bf16x8 __attribute__((ext_vector_type(8)));
typedef float floatx4 __attribute__((ext_vector_type(4)));

// ---- workspace layout (bytes) ----
// rp   : int[100001]            @ 0
// w1t  : ushort[256*512]        @ 400016
// w2t  : ushort[64*256]         @ 662160
// h1   : ushort[100000*256]     @ 694928   (dead after gemm2; bB aliases it)
// bB   : ushort[4 panels]       @ 694928   (alias of h1)
// fA   : float[100000*64]       @ 51894928
// fB   : float[100000*64]       @ 77494928
// bA   : ushort[4 panels]       @ 103094928
#define WS_ROWPTR 0
#define WS_W1T    400016
#define WS_W2T    662160
#define WS_H1     694928
#define WS_BB     694928
#define WS_FA     51894928
#define WS_FB     77494928
#define WS_BA     103094928

// ---------------- weight transpose + bf16 convert ----------------
__global__ __launch_bounds__(256) void prep_weights(
    const float* __restrict__ W1, const float* __restrict__ W2,
    unsigned short* __restrict__ w1t, unsigned short* __restrict__ w2t) {
  int tid = blockIdx.x * 256 + threadIdx.x;
  if (tid < IN_DIM * HIDDEN) {
    int n = tid >> 9;
    int k = tid & 511;
    __bf16 v = (__bf16)W1[k * HIDDEN + n];
    w1t[tid] = __builtin_bit_cast(unsigned short, v);
  } else {
    int idx = tid - IN_DIM * HIDDEN;
    if (idx < HIDDEN * NCLS) {
      int n = idx >> 8;
      int k = idx & 255;
      __bf16 v = (__bf16)W2[k * NCLS + n];
      w2t[idx] = __builtin_bit_cast(unsigned short, v);
    }
  }
}

// ---------------- row_ptr via binary search over sorted edge_row ----------------
__global__ __launch_bounds__(256) void build_rowptr(
    const int* __restrict__ erow, int* __restrict__ rp) {
  int r = blockIdx.x * 256 + threadIdx.x;
  if (r > M_NODES) return;
  if (r == M_NODES) { rp[r] = NUM_EDGES; return; }
  int lo = 0, hi = NUM_EDGES;
  while (lo < hi) {
    int mid = (lo + hi) >> 1;
    if (erow[mid] < r) lo = mid + 1; else hi = mid;
  }
  rp[r] = lo;
}

// ---------------- GEMM1: h1 = relu(x @ W1 + b1), bf16 out ----------------
__global__ __launch_bounds__(256) void gemm1(
    const float* __restrict__ x, const unsigned short* __restrict__ w1t,
    const float* __restrict__ b1, unsigned short* __restrict__ h1) {
  __shared__ float xs[32 * 68];
  const int wave = threadIdx.x >> 6, lane = threadIdx.x & 63;
  const int m0 = blockIdx.x * 32;
  const int n0 = wave * 64;
  const int l15 = lane & 15, quad = lane >> 4;
  const int t = threadIdx.x;

  floatx4 pre[2];
#pragma unroll
  for (int j = 0; j < 2; j++) {
    const int i = t * 2 + j;
    pre[j] = *(const floatx4*)(x + (size_t)(m0 + (i >> 4)) * IN_DIM + (i & 15) * 4);
  }

  floatx4 acc[2][4] = {};
  for (int kb = 0; kb < IN_DIM; kb += 64) {
    __syncthreads();
#pragma unroll
    for (int j = 0; j < 2; j++) {
      const int i = t * 2 + j;
      *(floatx4*)(xs + (i >> 4) * 68 + (i & 15) * 4) = pre[j];
    }
    __syncthreads();
    if (kb + 64 < IN_DIM) {
#pragma unroll
      for (int j = 0; j < 2; j++) {
        const int i = t * 2 + j;
        pre[j] = *(const floatx4*)(x + (size_t)(m0 + (i >> 4)) * IN_DIM + kb + 64 + (i & 15) * 4);
      }
    }

    bf16x8 afrag[2][2];
    bf16x8 bfrag[2][4];
#pragma unroll
    for (int ks = 0; ks < 2; ks++) {
#pragma unroll
      for (int tm = 0; tm < 2; tm++) {
        const float* p = xs + (tm * 16 + l15) * 68 + ks * 32 + quad * 8;
        floatx4 a0 = *(const floatx4*)p;
        floatx4 a1 = *(const floatx4*)(p + 4);
        bf16x8 f;
        f[0] = (__bf16)a0[0]; f[1] = (__bf16)a0[1]; f[2] = (__bf16)a0[2]; f[3] = (__bf16)a0[3];
        f[4] = (__bf16)a1[0]; f[5] = (__bf16)a1[1]; f[6] = (__bf16)a1[2]; f[7] = (__bf16)a1[3];
        afrag[ks][tm] = f;
      }
      const int k = kb + ks * 32 + quad * 8;
#pragma unroll
      for (int tn = 0; tn < 4; tn++)
        bfrag[ks][tn] = *(const bf16x8*)(w1t + (size_t)(n0 + tn * 16 + l15) * IN_DIM + k);
    }
#pragma unroll
    for (int ks = 0; ks < 2; ks++)
#pragma unroll
      for (int tm = 0; tm < 2; tm++)
#pragma unroll
        for (int tn = 0; tn < 4; tn++)
          acc[tm][tn] = __builtin_amdgcn_mfma_f32_16x16x32_bf16(afrag[ks][tm], bfrag[ks][tn], acc[tm][tn], 0, 0, 0);
  }

#pragma unroll
  for (int tm = 0; tm < 2; tm++)
#pragma unroll
    for (int tn = 0; tn < 4; tn++) {
      const int col = n0 + tn * 16 + l15;
      const float bias = b1[col];
#pragma unroll
      for (int r = 0; r < 4; r++) {
        const int row = m0 + tm * 16 + quad * 4 + r;
        float v = acc[tm][tn][r] + bias;
        v = v > 0.0f ? v : 0.0f;
        __bf16 bv = (__bf16)v;
        h1[(size_t)row * HIDDEN + col] = __builtin_bit_cast(unsigned short, bv);
      }
    }
}

// ---------------- GEMM2: T0 = h1 @ W2 + b2 -> fp32 (row-major) + bf16 (PANELS) ----
__global__ __launch_bounds__(256) void gemm2(
    const unsigned short* __restrict__ h1, const unsigned short* __restrict__ w2t,
    const float* __restrict__ b2, float* __restrict__ t0f,
    unsigned short* __restrict__ t0b) {
  const int wave = threadIdx.x >> 6, lane = threadIdx.x & 63;
  const int m0 = blockIdx.x * 128 + wave * 32;
  if (m0 >= M_NODES) return;
  const int l15 = lane & 15, quad = lane >> 4;

  floatx4 acc[2][4] = {};
  for (int kb = 0; kb < HIDDEN; kb += 32) {
    const int k = kb + quad * 8;
    bf16x8 afrag[2], bfrag[4];
#pragma unroll
    for (int tm = 0; tm < 2; tm++)
      afrag[tm] = *(const bf16x8*)(h1 + (size_t)(m0 + tm * 16 + l15) * HIDDEN + k);
#pragma unroll
    for (int tn = 0; tn < 4; tn++)
      bfrag[tn] = *(const bf16x8*)(w2t + (size_t)(tn * 16 + l15) * HIDDEN + k);
#pragma unroll
    for (int tm = 0; tm < 2; tm++)
#pragma unroll
      for (int tn = 0; tn < 4; tn++)
        acc[tm][tn] = __builtin_amdgcn_mfma_f32_16x16x32_bf16(afrag[tm], bfrag[tn], acc[tm][tn], 0, 0, 0);
  }

#pragma unroll
  for (int tm = 0; tm < 2; tm++)
#pragma unroll
    for (int tn = 0; tn < 4; tn++) {
      const int col = tn * 16 + l15;
      const float bias = b2[col];
#pragma unroll
      for (int r = 0; r < 4; r++) {
        const int row = m0 + tm * 16 + quad * 4 + r;
        const float v = acc[tm][tn][r] + bias;
        t0f[(size_t)row * NCLS + col] = v;
        __bf16 bv = (__bf16)v;
        // panel layout: group tn, inner col l15
        t0b[(size_t)tn * PANEL + (size_t)row * 16 + l15] = __builtin_bit_cast(unsigned short, bv);
      }
    }
}

// ---------------- per-lane row gather from a 16-col PANEL ----------------
__device__ __forceinline__ float row_gather1(
    const int* __restrict__ rp, const int* __restrict__ cols,
    const float* __restrict__ vals, const __bf16* __restrict__ pan,
    int r, int c15) {
  int e = rp[r];
  const int re = rp[r + 1];
  float a[8] = {0, 0, 0, 0, 0, 0, 0, 0};
  for (; e + 8 <= re; e += 8) {
    int ce[8];
#pragma unroll
    for (int j = 0; j < 8; j++) ce[j] = cols[e + j];
    float ge[8];
#pragma unroll
    for (int j = 0; j < 8; j++) ge[j] = (float)pan[(size_t)ce[j] * 16 + c15];
#pragma unroll
    for (int j = 0; j < 8; j++) a[j] += vals[e + j] * ge[j];
  }
  for (; e < re; ++e) a[0] += vals[e] * (float)pan[(size_t)cols[e] * 16 + c15];
  return ((a[0] + a[1]) + (a[2] + a[3])) + ((a[4] + a[5]) + (a[6] + a[7]));
}

// XCD-aware decomposition: blockIdx%8 -> XCD (round-robin). Col group
// g = (blockIdx%8)>>1 so XCD pair {2g,2g+1} only gathers from panel g
// (100000*16*2B = 3.2 MB < 4 MB per-XCD L2 -> L2-resident after warmup).
// Wave = 4 rows x 16 cols; block = 16 rows. grid = (100000/16)*4 = 25000.
__device__ __forceinline__ void spmm_map(int b, int tid, int& r, int& g, int& c15) {
  const int slot = b & 7;
  g = slot >> 1;
  const int row_blk = (b >> 3) * 2 + (slot & 1);  // 0..6249
  const int wave = tid >> 6, l = tid & 63;
  r = row_blk * 16 + wave * 4 + (l >> 4);
  c15 = l & 15;
}

// ---------------- SpMM first: T1 = L T0 ; z = g0*T0 + g1*T1 ----------------
__global__ __launch_bounds__(256) void spmm_first(
    const int* __restrict__ rp, const int* __restrict__ cols,
    const float* __restrict__ vals, const __bf16* __restrict__ t0b,
    const float* __restrict__ t0f, float* __restrict__ t1f,
    unsigned short* __restrict__ t1b, const float* __restrict__ gamma,
    float* __restrict__ z) {
  int r, g, c15;
  spmm_map(blockIdx.x, threadIdx.x, r, g, c15);
  const float s = row_gather1(rp, cols, vals, t0b + (size_t)g * PANEL, r, c15);
  const size_t o = (size_t)r * NCLS + g * 16 + c15;
  t1f[o] = s;
  __bf16 bv = (__bf16)s;
  t1b[(size_t)g * PANEL + (size_t)r * 16 + c15] = __builtin_bit_cast(unsigned short, bv);
  z[o] = gamma[0] * t0f[o] + gamma[1] * s;
}

// ---------------- SpMM step: Tn = 2 L Tc - Tp (in place over Tp); z += g[k]*Tn ----
__global__ __launch_bounds__(256) void spmm_step(
    const int* __restrict__ rp, const int* __restrict__ cols,
    const float* __restrict__ vals, const __bf16* __restrict__ tcb,
    float* __restrict__ tpf, unsigned short* __restrict__ tnb,
    const float* __restrict__ gamma, int kidx, float* __restrict__ z) {
  int r, g, c15;
  spmm_map(blockIdx.x, threadIdx.x, r, g, c15);
  const float s = row_gather1(rp, cols, vals, tcb + (size_t)g * PANEL, r, c15);
  const size_t o = (size_t)r * NCLS + g * 16 + c15;
  const float tn = 2.0f * s - tpf[o];
  tpf[o] = tn;
  __bf16 bv = (__bf16)tn;
  tnb[(size_t)g * PANEL + (size_t)r * 16 + c15] = __builtin_bit_cast(unsigned short, bv);
  z[o] += gamma[kidx] * tn;
}

extern "C" void kernel_launch(void* const* d_in, const int* in_sizes, int n_in,
                              void* d_out, int out_size, void* d_ws, size_t ws_size,
                              hipStream_t stream) {
  const float* x     = (const float*)d_in[0];
  const int*   erow  = (const int*)d_in[1];
  const int*   ecol  = (const int*)d_in[2];
  const float* evals = (const float*)d_in[3];
  const float* W1    = (const float*)d_in[4];
  const float* b1    = (const float*)d_in[5];
  const float* W2    = (const float*)d_in[6];
  const float* b2    = (const float*)d_in[7];
  const float* gamma = (const float*)d_in[8];

  char* ws = (char*)d_ws;
  int*            rp  = (int*)(ws + WS_ROWPTR);
  unsigned short* w1t = (unsigned short*)(ws + WS_W1T);
  unsigned short* w2t = (unsigned short*)(ws + WS_W2T);
  unsigned short* h1  = (unsigned short*)(ws + WS_H1);
  float*          fA  = (float*)(ws + WS_FA);
  float*          fB  = (float*)(ws + WS_FB);
  unsigned short* bA  = (unsigned short*)(ws + WS_BA);
  unsigned short* bB  = (unsigned short*)(ws + WS_BB);
  float*          z   = (float*)d_out;

  prep_weights<<<576, 256, 0, stream>>>(W1, W2, w1t, w2t);
  build_rowptr<<<(M_NODES + 256) / 256, 256, 0, stream>>>(erow, rp);
  gemm1<<<M_NODES / 32, 256, 0, stream>>>(x, w1t, b1, h1);
  gemm2<<<(M_NODES + 127) / 128, 256, 0, stream>>>(h1, w2t, b2, fA, bA);

  const int spmm_grid = (M_NODES / 16) * 4;  // 25000
  spmm_first<<<spmm_grid, 256, 0, stream>>>(rp, ecol, evals, (const __bf16*)bA,
                                            fA, fB, bB, gamma, z);

  float*          fprev = fA;
  float*          fothr = fB;
  unsigned short* bcur  = bB;
  unsigned short* bnext = bA;
  for (int k = 2; k <= 8; ++k) {
    spmm_step<<<spmm_grid, 256, 0, stream>>>(rp, ecol, evals, (const __bf16*)bcur,
                                             fprev, bnext, gamma, k, z);
    float* tf = fprev; fprev = fothr; fothr = tf;
    unsigned short* tb = bcur; bcur = bnext; bnext = tb;
  }
}